// Round 3
// baseline (1833.188 us; speedup 1.0000x reference)
//
#include <hip/hip_runtime.h>

typedef _Float16 h16;
typedef __attribute__((ext_vector_type(4))) _Float16 h16x4;
typedef __attribute__((ext_vector_type(8))) _Float16 h16x8;
typedef __attribute__((ext_vector_type(4))) float f32x4;

#define SCALE 0.17677669529663687f
#define MFMA16(a, b, c) __builtin_amdgcn_mfma_f32_16x16x16f16(a, b, c, 0, 0, 0)
#define MFMA32(a, b, c) __builtin_amdgcn_mfma_f32_16x16x32_f16(a, b, c, 0, 0, 0)

// workspace layout (bytes)
#define O_BYTES 205520896ULL              // 200704*512*2 (pre-proj output, fp16)
#define W1T_OFF (O_BYTES)                 // w1T fp16 [1536][512]: 1572864
#define W2T_OFF (W1T_OFF + 1572864ULL)    // w2T fp16 [512 out][512 k]: 524288
#define BT_OFF  (W2T_OFF + 524288ULL)     // biasT f32 [16][64 q][64 j]: 262144

// ---------------- x fp32 -> fp16 (into d_out; dead until wa_proj overwrites) ----------------
__global__ __launch_bounds__(256) void wa_convert_x(
    const float* __restrict__ x, h16* __restrict__ x16) {
  size_t i = ((size_t)blockIdx.x * 256 + threadIdx.x) * 8;
  float4 a = *(const float4*)(x + i);
  float4 b = *(const float4*)(x + i + 4);
  h16x8 h = { (h16)a.x, (h16)a.y, (h16)a.z, (h16)a.w,
              (h16)b.x, (h16)b.y, (h16)b.z, (h16)b.w };
  *(h16x8*)(x16 + i) = h;
}

// ---------------- qkv_w [512c][1536o] fp32 -> w1T [1536o][512c] fp16 ----------------
__global__ __launch_bounds__(256) void wa_transpose_w1(
    const float* __restrict__ qkv_w, h16* __restrict__ w1T) {
  __shared__ h16 T[32][33];
  int tx = threadIdx.x & 31, ty = threadIdx.x >> 5;   // 32 x 8
  int bo = blockIdx.x % 48, bc = blockIdx.x / 48;     // 48 o-tiles, 16 c-tiles
  #pragma unroll
  for (int i = 0; i < 4; ++i) {
    int c = bc * 32 + ty + 8 * i, o = bo * 32 + tx;
    T[ty + 8 * i][tx] = (h16)qkv_w[c * 1536 + o];
  }
  __syncthreads();
  #pragma unroll
  for (int i = 0; i < 4; ++i) {
    int o_l = ty + 8 * i;
    w1T[(size_t)(bo * 32 + o_l) * 512 + bc * 32 + tx] = T[tx][o_l];
  }
}

// ---------------- proj_w [512c][512o] fp32 -> w2T [512o][512c] fp16 ----------------
__global__ __launch_bounds__(256) void wa_transpose_w2(
    const float* __restrict__ proj_w, h16* __restrict__ w2T) {
  __shared__ h16 T[32][33];
  int tx = threadIdx.x & 31, ty = threadIdx.x >> 5;
  int bo = blockIdx.x & 15, bc = blockIdx.x >> 4;     // 16 x 16 tiles
  #pragma unroll
  for (int i = 0; i < 4; ++i) {
    int c = bc * 32 + ty + 8 * i, o = bo * 32 + tx;
    T[ty + 8 * i][tx] = (h16)proj_w[c * 512 + o];
  }
  __syncthreads();
  #pragma unroll
  for (int i = 0; i < 4; ++i) {
    int o_l = ty + 8 * i;
    w2T[(size_t)(bo * 32 + o_l) * 512 + bc * 32 + tx] = T[tx][o_l];
  }
}

// ---------------- relative-position bias: biasT[h][q][j], -1e30 where padded ----------------
__global__ __launch_bounds__(256) void wa_build_bias(
    const float* __restrict__ table, float* __restrict__ biasT) {
  int idx = blockIdx.x * 256 + threadIdx.x;  // 65536
  int h = idx >> 12, q = (idx >> 6) & 63, j = idx & 63;
  float v = -1e30f;
  if (j < 49 && q < 49) {
    int rel = (q / 7 - j / 7 + 6) * 13 + (q % 7 - j % 7 + 6);
    v = table[rel * 16 + h];
  }
  biasT[idx] = v;
}

// ---------------- fused QKV projection + window attention ----------------
// grid: 2048 window-pairs * 4 head-groups (XCD-swizzled); block 256 = 4 waves; wave = one head,
// processing TWO windows (M=128) per block to amortize w1T staging.
// GEMMs use 16x16x32 f16 MFMA (A/B frag = 8 contiguous k); attention uses 16x16x16 (register frags).
// LDS: XOR-swizzled 128B rows (chunk ^= row&7) -> conflict-free b128, no padding. Total = 64 KiB.
__global__ __launch_bounds__(256, 2) void wa_qkv_attn(
    const h16* __restrict__ x16, const float* __restrict__ qkv_b,
    const h16* __restrict__ w1T, const float* __restrict__ biasT,
    h16* __restrict__ O) {
  __shared__ __align__(16) char lds[65536];
  char* Xc = lds;            // 2 windows x [64 rows][64 k] h16, swizzled (16384 B)
  char* Wc = lds + 16384;    // [384 rows][64 k] h16, swizzled (49152 B)
  const int tid = threadIdx.x;
  const int wave = tid >> 6, lane = tid & 63;
  const int l15 = lane & 15, lg = lane >> 4;
  const int lbid = (blockIdx.x & 7) * 1024 + (blockIdx.x >> 3);  // XCD swizzle (8192 % 8 == 0)
  const int wpair = lbid >> 2, g = lbid & 3;
  const int head = g * 4 + wave;
  const size_t rowbase = (size_t)wpair * 98;

  // zero pad rows (49..63 of each window, full 64-col width), once
  if (tid < 240) {
    int win = tid >= 120, t = tid - 120 * win;
    int lrow = win * 64 + 49 + (t >> 3), c = t & 7;
    *(h16x8*)(Xc + lrow * 128 + ((c ^ (lrow & 7)) << 4)) = (h16x8){0,0,0,0,0,0,0,0};
  }

  f32x4 accQ[2][2][4], accK[2][2][4], accV[2][4][2];
  #pragma unroll
  for (int win = 0; win < 2; ++win)
    #pragma unroll
    for (int d = 0; d < 2; ++d)
      #pragma unroll
      for (int t = 0; t < 4; ++t) {
        accQ[win][d][t] = (f32x4){0.f, 0.f, 0.f, 0.f};
        accK[win][d][t] = (f32x4){0.f, 0.f, 0.f, 0.f};
        accV[win][t][d] = (f32x4){0.f, 0.f, 0.f, 0.f};
      }

  for (int kt = 0; kt < 8; ++kt) {      // BK = 64
    // stage: x 98 rows x 8 chunks (784) + w1T 384 rows x 8 chunks (3072) = 3856 chunks
    #pragma unroll
    for (int p = 0; p < 16; ++p) {
      int idx = tid + p * 256;
      if (idx < 3856) {
        if (idx < 784) {
          int r = idx >> 3, c = idx & 7;
          int win = (r >= 49), lrow = win * 64 + (r - 49 * win);
          h16x8 v = *(const h16x8*)(x16 + (rowbase + r) * 512 + kt * 64 + c * 8);
          *(h16x8*)(Xc + lrow * 128 + ((c ^ (lrow & 7)) << 4)) = v;
        } else {
          int widx = idx - 784;
          int row = widx >> 3, c = widx & 7;
          int o = ((row >> 7) << 9) + g * 128 + (row & 127);
          h16x8 v = *(const h16x8*)(w1T + (size_t)o * 512 + kt * 64 + c * 8);
          *(h16x8*)(Wc + row * 128 + ((c ^ (row & 7)) << 4)) = v;
        }
      }
    }
    __syncthreads();
    #pragma unroll
    for (int kh = 0; kh < 2; ++kh) {
      const int cc = kh * 4 + lg;        // logical 16B chunk = k-cols 8*cc..8*cc+7
      const int sw = (l15 & 7);          // row&7 for all frag rows
      h16x8 wq[2], wk[2], wv[2];
      #pragma unroll
      for (int d = 0; d < 2; ++d) {
        int rq = wave * 32 + 16 * d + l15;
        wq[d] = *(const h16x8*)(Wc + rq * 128 + ((cc ^ sw) << 4));
        wk[d] = *(const h16x8*)(Wc + (128 + rq) * 128 + ((cc ^ sw) << 4));
        wv[d] = *(const h16x8*)(Wc + (256 + rq) * 128 + ((cc ^ sw) << 4));
      }
      #pragma unroll
      for (int win = 0; win < 2; ++win) {
        h16x8 xf[4];
        #pragma unroll
        for (int t = 0; t < 4; ++t) {
          int rx = win * 64 + 16 * t + l15;
          xf[t] = *(const h16x8*)(Xc + rx * 128 + ((cc ^ sw) << 4));
        }
        #pragma unroll
        for (int d = 0; d < 2; ++d)
          #pragma unroll
          for (int t = 0; t < 4; ++t) {
            accQ[win][d][t] = MFMA32(wq[d], xf[t], accQ[win][d][t]);
            accK[win][d][t] = MFMA32(wk[d], xf[t], accK[win][d][t]);
            accV[win][t][d] = MFMA32(xf[t], wv[d], accV[win][t][d]);
          }
      }
    }
    __syncthreads();
  }

  // ---- per-head biases (shared by both windows) ----
  float bq[2][4], bk[2][4], bv[2];
  #pragma unroll
  for (int d = 0; d < 2; ++d) {
    #pragma unroll
    for (int r = 0; r < 4; ++r) {
      bq[d][r] = qkv_b[head * 32 + 16 * d + 4 * lg + r];
      bk[d][r] = qkv_b[512 + head * 32 + 16 * d + 4 * lg + r];
    }
    bv[d] = qkv_b[1024 + head * 32 + 16 * d + l15];
  }
  const float* bT = biasT + head * 4096;
  h16* Ob = (h16*)(lds + wave * 5120);   // per-wave [64][40] bounce; aliases dead staging

  #pragma unroll
  for (int win = 0; win < 2; ++win) {
    // epilogue: bias (+scale Q), convert to fp16 operand frags in registers
    h16x4 Qh[2][4], Kh[2][4], Vh[4][2];
    #pragma unroll
    for (int d = 0; d < 2; ++d)
      #pragma unroll
      for (int t = 0; t < 4; ++t)
        #pragma unroll
        for (int r = 0; r < 4; ++r) {
          Qh[d][t][r] = (h16)((accQ[win][d][t][r] + bq[d][r]) * SCALE);
          Kh[d][t][r] = (h16)(accK[win][d][t][r] + bk[d][r]);
          Vh[t][d][r] = (h16)(accV[win][t][d][r] + bv[d]);
        }

    // S^T = K Q^T (x16 MFMAs, register operands)
    f32x4 st[4][4];
    #pragma unroll
    for (int a = 0; a < 4; ++a)
      #pragma unroll
      for (int b = 0; b < 4; ++b) st[a][b] = (f32x4){0.f, 0.f, 0.f, 0.f};
    #pragma unroll
    for (int d = 0; d < 2; ++d)
      #pragma unroll
      for (int jt = 0; jt < 4; ++jt)
        #pragma unroll
        for (int qt = 0; qt < 4; ++qt)
          st[jt][qt] = MFMA16(Kh[d][jt], Qh[d][qt], st[jt][qt]);

    // bias + in-register softmax over j
    float rinv[4];
    #pragma unroll
    for (int qt = 0; qt < 4; ++qt) {
      int q = 16 * qt + l15;
      float mx = -3.4e38f;
      #pragma unroll
      for (int jt = 0; jt < 4; ++jt) {
        float4 bvv = *(const float4*)(bT + q * 64 + 16 * jt + 4 * lg);
        #pragma unroll
        for (int r = 0; r < 4; ++r) {
          float v = st[jt][qt][r] + ((const float*)&bvv)[r];
          st[jt][qt][r] = v;
          mx = fmaxf(mx, v);
        }
      }
      mx = fmaxf(mx, __shfl_xor(mx, 16, 64));
      mx = fmaxf(mx, __shfl_xor(mx, 32, 64));
      float sum = 0.f;
      #pragma unroll
      for (int jt = 0; jt < 4; ++jt)
        #pragma unroll
        for (int r = 0; r < 4; ++r) {
          float p = __expf(st[jt][qt][r] - mx);
          st[jt][qt][r] = p;
          sum += p;
        }
      sum += __shfl_xor(sum, 16, 64);
      sum += __shfl_xor(sum, 32, 64);
      rinv[qt] = 1.0f / sum;
    }

    // P^T frags already in B-operand layout
    h16x4 pf[4][4];
    #pragma unroll
    for (int jt = 0; jt < 4; ++jt)
      #pragma unroll
      for (int qt = 0; qt < 4; ++qt)
        pf[jt][qt] = (h16x4){ (h16)st[jt][qt][0], (h16)st[jt][qt][1],
                              (h16)st[jt][qt][2], (h16)st[jt][qt][3] };

    // O^T = V^T P^T (x16 MFMAs)
    f32x4 ot[2][4];
    #pragma unroll
    for (int d = 0; d < 2; ++d)
      #pragma unroll
      for (int qt = 0; qt < 4; ++qt) ot[d][qt] = (f32x4){0.f, 0.f, 0.f, 0.f};
    #pragma unroll
    for (int jt = 0; jt < 4; ++jt)
      #pragma unroll
      for (int d = 0; d < 2; ++d)
        #pragma unroll
        for (int qt = 0; qt < 4; ++qt)
          ot[d][qt] = MFMA16(Vh[jt][d], pf[jt][qt], ot[d][qt]);

    // normalize, bounce O^T -> row-major per-wave LDS, coalesced copy-out
    #pragma unroll
    for (int d = 0; d < 2; ++d)
      #pragma unroll
      for (int qt = 0; qt < 4; ++qt) {
        h16x4 ov;
        #pragma unroll
        for (int r = 0; r < 4; ++r) ov[r] = (h16)(ot[d][qt][r] * rinv[qt]);
        *(h16x4*)(Ob + (16 * qt + l15) * 40 + 16 * d + 4 * lg) = ov;
      }
    if (lane < 49) {
      h16* gdst = O + (rowbase + win * 49 + lane) * 512 + head * 32;
      #pragma unroll
      for (int c = 0; c < 4; ++c)
        *(h16x8*)(gdst + c * 8) = *(const h16x8*)(Ob + lane * 40 + c * 8);
    }
  }
}

// ---------------- output projection: out = O @ w2 + proj_b ----------------
// 128x128 tile, 4 waves of 64x64, BK=64, x32 MFMAs, swizzled LDS, w2 pre-transposed.
__global__ __launch_bounds__(256, 3) void wa_proj(
    const h16* __restrict__ O, const h16* __restrict__ w2T,
    const float* __restrict__ proj_b, float* __restrict__ out) {
  __shared__ __align__(16) char lds[32768];
  char* Ac = lds;            // [128 rows][64 k] h16, swizzled
  char* Bc = lds + 16384;    // [128 cols][64 k] h16, swizzled
  const int tid = threadIdx.x;
  const int wave = tid >> 6, lane = tid & 63;
  const int l15 = lane & 15, lg = lane >> 4;
  const int lbid = (blockIdx.x & 7) * 784 + (blockIdx.x >> 3);  // XCD swizzle (6272 % 8 == 0)
  const int rowt = lbid >> 2, colt = lbid & 3;
  const int wr = wave >> 1, wc = wave & 1;

  f32x4 acc[4][4];
  #pragma unroll
  for (int a = 0; a < 4; ++a)
    #pragma unroll
    for (int b = 0; b < 4; ++b) acc[a][b] = (f32x4){0.f, 0.f, 0.f, 0.f};

  for (int kt = 0; kt < 8; ++kt) {
    #pragma unroll
    for (int p = 0; p < 8; ++p) {        // 1024 A chunks + 1024 B chunks
      int idx = tid + p * 256;
      int r = (idx >> 3) & 127, c = idx & 7;
      const h16* src = (idx < 1024)
          ? (O   + (size_t)(rowt * 128 + r) * 512 + kt * 64 + c * 8)
          : (w2T + (size_t)(colt * 128 + r) * 512 + kt * 64 + c * 8);
      char* dst = ((idx < 1024) ? Ac : Bc) + r * 128 + ((c ^ (r & 7)) << 4);
      *(h16x8*)dst = *(const h16x8*)src;
    }
    __syncthreads();
    #pragma unroll
    for (int kh = 0; kh < 2; ++kh) {
      const int cc = kh * 4 + lg;
      const int sw = (l15 & 7);
      h16x8 af[4], bf[4];
      #pragma unroll
      for (int mt = 0; mt < 4; ++mt) {
        int r = wr * 64 + 16 * mt + l15;
        af[mt] = *(const h16x8*)(Ac + r * 128 + ((cc ^ sw) << 4));
      }
      #pragma unroll
      for (int nt = 0; nt < 4; ++nt) {
        int r = wc * 64 + 16 * nt + l15;
        bf[nt] = *(const h16x8*)(Bc + r * 128 + ((cc ^ sw) << 4));
      }
      #pragma unroll
      for (int mt = 0; mt < 4; ++mt)
        #pragma unroll
        for (int nt = 0; nt < 4; ++nt)
          acc[mt][nt] = MFMA32(af[mt], bf[nt], acc[mt][nt]);
    }
    __syncthreads();
  }
  #pragma unroll
  for (int nt = 0; nt < 4; ++nt) {
    int col = colt * 128 + wc * 64 + nt * 16 + l15;
    float pb = proj_b[col];
    #pragma unroll
    for (int mt = 0; mt < 4; ++mt) {
      int row = rowt * 128 + wr * 64 + mt * 16 + 4 * lg;
      #pragma unroll
      for (int r = 0; r < 4; ++r)
        out[(size_t)(row + r) * 512 + col] = acc[mt][nt][r] + pb;
    }
  }
}

extern "C" void kernel_launch(void* const* d_in, const int* in_sizes, int n_in,
                              void* d_out, int out_size, void* d_ws, size_t ws_size,
                              hipStream_t stream) {
  const float* x          = (const float*)d_in[0];
  const float* qkv_w      = (const float*)d_in[1];
  const float* qkv_b      = (const float*)d_in[2];
  const float* proj_w     = (const float*)d_in[3];
  const float* proj_b     = (const float*)d_in[4];
  const float* bias_table = (const float*)d_in[5];
  float* out = (float*)d_out;

  char* ws = (char*)d_ws;
  h16*   O     = (h16*)ws;
  h16*   w1T   = (h16*)(ws + W1T_OFF);
  h16*   w2T   = (h16*)(ws + W2T_OFF);
  float* biasT = (float*)(ws + BT_OFF);
  h16*   x16   = (h16*)d_out;  // d_out is dead until wa_proj overwrites it

  wa_convert_x<<<50176, 256, 0, stream>>>(x, x16);
  wa_transpose_w1<<<768, 256, 0, stream>>>(qkv_w, w1T);
  wa_transpose_w2<<<256, 256, 0, stream>>>(proj_w, w2T);
  wa_build_bias<<<256, 256, 0, stream>>>(bias_table, biasT);
  wa_qkv_attn<<<2048 * 4, 256, 0, stream>>>(x16, qkv_b, w1T, biasT, O);
  wa_proj<<<1568 * 4, 256, 0, stream>>>(O, w2T, proj_b, out);
}

// Round 4
// 1328.420 us; speedup vs baseline: 1.3800x; 1.3800x over previous
//
#include <hip/hip_runtime.h>

typedef _Float16 h16;
typedef __attribute__((ext_vector_type(4))) _Float16 h16x4;
typedef __attribute__((ext_vector_type(8))) _Float16 h16x8;
typedef __attribute__((ext_vector_type(4))) float f32x4;

#define SCALE 0.17677669529663687f
#define MFMA16(a, b, c) __builtin_amdgcn_mfma_f32_16x16x16f16(a, b, c, 0, 0, 0)
#define MFMA32(a, b, c) __builtin_amdgcn_mfma_f32_16x16x32_f16(a, b, c, 0, 0, 0)

// workspace layout (bytes)
#define O_BYTES 205520896ULL              // 200704*512*2 (pre-proj output, fp16)
#define W1T_OFF (O_BYTES)                 // w1T fp16 [1536][512]: 1572864
#define W2T_OFF (W1T_OFF + 1572864ULL)    // w2T fp16 [512 out][512 k]: 524288
#define BT_OFF  (W2T_OFF + 524288ULL)     // biasT f32 [16][64 q][64 j]: 262144

// ---------------- x fp32 -> fp16 (into d_out; dead until wa_proj overwrites) ----------------
__global__ __launch_bounds__(256) void wa_convert_x(
    const float* __restrict__ x, h16* __restrict__ x16) {
  size_t i = ((size_t)blockIdx.x * 256 + threadIdx.x) * 8;
  float4 a = *(const float4*)(x + i);
  float4 b = *(const float4*)(x + i + 4);
  h16x8 h = { (h16)a.x, (h16)a.y, (h16)a.z, (h16)a.w,
              (h16)b.x, (h16)b.y, (h16)b.z, (h16)b.w };
  *(h16x8*)(x16 + i) = h;
}

// ---------------- qkv_w [512c][1536o] fp32 -> w1T [1536o][512c] fp16 ----------------
__global__ __launch_bounds__(256) void wa_transpose_w1(
    const float* __restrict__ qkv_w, h16* __restrict__ w1T) {
  __shared__ h16 T[32][33];
  int tx = threadIdx.x & 31, ty = threadIdx.x >> 5;   // 32 x 8
  int bo = blockIdx.x % 48, bc = blockIdx.x / 48;     // 48 o-tiles, 16 c-tiles
  #pragma unroll
  for (int i = 0; i < 4; ++i) {
    int c = bc * 32 + ty + 8 * i, o = bo * 32 + tx;
    T[ty + 8 * i][tx] = (h16)qkv_w[c * 1536 + o];
  }
  __syncthreads();
  #pragma unroll
  for (int i = 0; i < 4; ++i) {
    int o_l = ty + 8 * i;
    w1T[(size_t)(bo * 32 + o_l) * 512 + bc * 32 + tx] = T[tx][o_l];
  }
}

// ---------------- proj_w [512c][512o] fp32 -> w2T [512o][512c] fp16 ----------------
__global__ __launch_bounds__(256) void wa_transpose_w2(
    const float* __restrict__ proj_w, h16* __restrict__ w2T) {
  __shared__ h16 T[32][33];
  int tx = threadIdx.x & 31, ty = threadIdx.x >> 5;
  int bo = blockIdx.x & 15, bc = blockIdx.x >> 4;     // 16 x 16 tiles
  #pragma unroll
  for (int i = 0; i < 4; ++i) {
    int c = bc * 32 + ty + 8 * i, o = bo * 32 + tx;
    T[ty + 8 * i][tx] = (h16)proj_w[c * 512 + o];
  }
  __syncthreads();
  #pragma unroll
  for (int i = 0; i < 4; ++i) {
    int o_l = ty + 8 * i;
    w2T[(size_t)(bo * 32 + o_l) * 512 + bc * 32 + tx] = T[tx][o_l];
  }
}

// ---------------- relative-position bias: biasT[h][q][j], -1e30 where padded ----------------
__global__ __launch_bounds__(256) void wa_build_bias(
    const float* __restrict__ table, float* __restrict__ biasT) {
  int idx = blockIdx.x * 256 + threadIdx.x;  // 65536
  int h = idx >> 12, q = (idx >> 6) & 63, j = idx & 63;
  float v = -1e30f;
  if (j < 49 && q < 49) {
    int rel = (q / 7 - j / 7 + 6) * 13 + (q % 7 - j % 7 + 6);
    v = table[rel * 16 + h];
  }
  biasT[idx] = v;
}

// ---------------- fused QKV projection + window attention ----------------
// grid: 4096 windows * 4 head-groups (XCD-swizzled); block 256 = 4 waves; wave = one head.
// 1 window/block (acc = 96 VGPR, no spill), BK=64, x32 MFMA for GEMM, x16 for attention.
// T14 async-stage: next tile's 14 global loads issue BEFORE current tile's compute.
// LDS: XOR-swizzled 128B rows (chunk ^= row&7), 56 KiB -> 2 blocks/CU.
#define NCHUNK 3464   // 49*8 x-chunks + 384*8 w-chunks
__global__ __launch_bounds__(256, 1) void wa_qkv_attn(
    const h16* __restrict__ x16, const float* __restrict__ qkv_b,
    const h16* __restrict__ w1T, const float* __restrict__ biasT,
    h16* __restrict__ O) {
  __shared__ __align__(16) char lds[57344];
  char* Xc = lds;            // [64 rows][64 k] h16, swizzled (8192 B); rows 49..63 zero
  char* Wc = lds + 8192;     // [384 rows][64 k] h16, swizzled (49152 B)
  const int tid = threadIdx.x;
  const int wave = tid >> 6, lane = tid & 63;
  const int l15 = lane & 15, lg = lane >> 4;
  const int lbid = (blockIdx.x & 7) * 2048 + (blockIdx.x >> 3);  // XCD swizzle (16384 % 8 == 0)
  const int w = lbid >> 2, g = lbid & 3;
  const int head = g * 4 + wave;
  const size_t rowbase = (size_t)w * 49;

  // per-thread staging addresses (constant across kt except the k-offset)
  const int cidx0 = tid;                 // chunks tid, tid+256, ... tid+13*256
  // zero pad rows (49..63, full 64-col width), once
  if (tid < 120) {
    int lrow = 49 + (tid >> 3), c = tid & 7;
    *(h16x8*)(Xc + lrow * 128 + ((c ^ (lrow & 7)) << 4)) = (h16x8){0,0,0,0,0,0,0,0};
  }

  f32x4 accQ[2][4], accK[2][4], accV[4][2];
  #pragma unroll
  for (int d = 0; d < 2; ++d)
    #pragma unroll
    for (int t = 0; t < 4; ++t) {
      accQ[d][t] = (f32x4){0.f, 0.f, 0.f, 0.f};
      accK[d][t] = (f32x4){0.f, 0.f, 0.f, 0.f};
      accV[t][d] = (f32x4){0.f, 0.f, 0.f, 0.f};
    }

  h16x8 pre[14];
  // ---- prologue: load tile 0 -> regs -> LDS ----
  #pragma unroll
  for (int p = 0; p < 14; ++p) {
    int idx = cidx0 + p * 256;
    if (idx < NCHUNK) {
      if (idx < 392) {
        int r = idx >> 3, c = idx & 7;
        pre[p] = *(const h16x8*)(x16 + (rowbase + r) * 512 + c * 8);
      } else {
        int widx = idx - 392;
        int row = widx >> 3, c = widx & 7;
        int o = ((row >> 7) << 9) + g * 128 + (row & 127);
        pre[p] = *(const h16x8*)(w1T + (size_t)o * 512 + c * 8);
      }
    }
  }
  #pragma unroll
  for (int p = 0; p < 14; ++p) {
    int idx = cidx0 + p * 256;
    if (idx < NCHUNK) {
      char* dst;
      if (idx < 392) {
        int r = idx >> 3, c = idx & 7;
        dst = Xc + r * 128 + ((c ^ (r & 7)) << 4);
      } else {
        int widx = idx - 392;
        int row = widx >> 3, c = widx & 7;
        dst = Wc + row * 128 + ((c ^ (row & 7)) << 4);
      }
      *(h16x8*)dst = pre[p];
    }
  }
  __syncthreads();

  for (int kt = 0; kt < 8; ++kt) {      // BK = 64
    // ---- issue next tile's loads (hide latency under compute) ----
    if (kt < 7) {
      #pragma unroll
      for (int p = 0; p < 14; ++p) {
        int idx = cidx0 + p * 256;
        if (idx < NCHUNK) {
          if (idx < 392) {
            int r = idx >> 3, c = idx & 7;
            pre[p] = *(const h16x8*)(x16 + (rowbase + r) * 512 + (kt + 1) * 64 + c * 8);
          } else {
            int widx = idx - 392;
            int row = widx >> 3, c = widx & 7;
            int o = ((row >> 7) << 9) + g * 128 + (row & 127);
            pre[p] = *(const h16x8*)(w1T + (size_t)o * 512 + (kt + 1) * 64 + c * 8);
          }
        }
      }
    }
    // ---- compute current tile ----
    #pragma unroll
    for (int kh = 0; kh < 2; ++kh) {
      const int cc = kh * 4 + lg;        // logical 16B chunk = k-cols 8*cc..8*cc+7
      const int sw = (l15 & 7);
      h16x8 wq[2], wk[2], wv[2], xf[4];
      #pragma unroll
      for (int d = 0; d < 2; ++d) {
        int rq = wave * 32 + 16 * d + l15;
        wq[d] = *(const h16x8*)(Wc + rq * 128 + ((cc ^ sw) << 4));
        wk[d] = *(const h16x8*)(Wc + (128 + rq) * 128 + ((cc ^ sw) << 4));
        wv[d] = *(const h16x8*)(Wc + (256 + rq) * 128 + ((cc ^ sw) << 4));
      }
      #pragma unroll
      for (int t = 0; t < 4; ++t) {
        int rx = 16 * t + l15;
        xf[t] = *(const h16x8*)(Xc + rx * 128 + ((cc ^ sw) << 4));
      }
      #pragma unroll
      for (int d = 0; d < 2; ++d)
        #pragma unroll
        for (int t = 0; t < 4; ++t) {
          accQ[d][t] = MFMA32(wq[d], xf[t], accQ[d][t]);
          accK[d][t] = MFMA32(wk[d], xf[t], accK[d][t]);
          accV[t][d] = MFMA32(xf[t], wv[d], accV[t][d]);
        }
    }
    __syncthreads();                    // all reads of LDS done
    if (kt < 7) {
      #pragma unroll
      for (int p = 0; p < 14; ++p) {    // write prefetched tile (compiler inserts vmcnt)
        int idx = cidx0 + p * 256;
        if (idx < NCHUNK) {
          char* dst;
          if (idx < 392) {
            int r = idx >> 3, c = idx & 7;
            dst = Xc + r * 128 + ((c ^ (r & 7)) << 4);
          } else {
            int widx = idx - 392;
            int row = widx >> 3, c = widx & 7;
            dst = Wc + row * 128 + ((c ^ (row & 7)) << 4);
          }
          *(h16x8*)dst = pre[p];
        }
      }
      __syncthreads();                  // writes visible before next compute
    }
  }

  // ---- per-head biases ----
  float bq[2][4], bk[2][4], bv[2];
  #pragma unroll
  for (int d = 0; d < 2; ++d) {
    #pragma unroll
    for (int r = 0; r < 4; ++r) {
      bq[d][r] = qkv_b[head * 32 + 16 * d + 4 * lg + r];
      bk[d][r] = qkv_b[512 + head * 32 + 16 * d + 4 * lg + r];
    }
    bv[d] = qkv_b[1024 + head * 32 + 16 * d + l15];
  }
  const float* bT = biasT + head * 4096;

  // ---- epilogue: bias (+scale Q), convert to fp16 operand frags in registers ----
  h16x4 Qh[2][4], Kh[2][4], Vh[4][2];
  #pragma unroll
  for (int d = 0; d < 2; ++d)
    #pragma unroll
    for (int t = 0; t < 4; ++t)
      #pragma unroll
      for (int r = 0; r < 4; ++r) {
        Qh[d][t][r] = (h16)((accQ[d][t][r] + bq[d][r]) * SCALE);
        Kh[d][t][r] = (h16)(accK[d][t][r] + bk[d][r]);
        Vh[t][d][r] = (h16)(accV[t][d][r] + bv[d]);
      }

  // ---- S^T = K Q^T (register operands) ----
  f32x4 st[4][4];
  #pragma unroll
  for (int a = 0; a < 4; ++a)
    #pragma unroll
    for (int b = 0; b < 4; ++b) st[a][b] = (f32x4){0.f, 0.f, 0.f, 0.f};
  #pragma unroll
  for (int d = 0; d < 2; ++d)
    #pragma unroll
    for (int jt = 0; jt < 4; ++jt)
      #pragma unroll
      for (int qt = 0; qt < 4; ++qt)
        st[jt][qt] = MFMA16(Kh[d][jt], Qh[d][qt], st[jt][qt]);

  // ---- bias + in-register softmax over j ----
  float rinv[4];
  #pragma unroll
  for (int qt = 0; qt < 4; ++qt) {
    int q = 16 * qt + l15;
    float mx = -3.4e38f;
    #pragma unroll
    for (int jt = 0; jt < 4; ++jt) {
      float4 bvv = *(const float4*)(bT + q * 64 + 16 * jt + 4 * lg);
      #pragma unroll
      for (int r = 0; r < 4; ++r) {
        float v = st[jt][qt][r] + ((const float*)&bvv)[r];
        st[jt][qt][r] = v;
        mx = fmaxf(mx, v);
      }
    }
    mx = fmaxf(mx, __shfl_xor(mx, 16, 64));
    mx = fmaxf(mx, __shfl_xor(mx, 32, 64));
    float sum = 0.f;
    #pragma unroll
    for (int jt = 0; jt < 4; ++jt)
      #pragma unroll
      for (int r = 0; r < 4; ++r) {
        float p = __expf(st[jt][qt][r] - mx);
        st[jt][qt][r] = p;
        sum += p;
      }
    sum += __shfl_xor(sum, 16, 64);
    sum += __shfl_xor(sum, 32, 64);
    rinv[qt] = 1.0f / sum;
  }

  // P^T frags already in B-operand layout
  h16x4 pf[4][4];
  #pragma unroll
  for (int jt = 0; jt < 4; ++jt)
    #pragma unroll
    for (int qt = 0; qt < 4; ++qt)
      pf[jt][qt] = (h16x4){ (h16)st[jt][qt][0], (h16)st[jt][qt][1],
                            (h16)st[jt][qt][2], (h16)st[jt][qt][3] };

  // ---- O^T = V^T P^T ----
  f32x4 ot[2][4];
  #pragma unroll
  for (int d = 0; d < 2; ++d)
    #pragma unroll
    for (int qt = 0; qt < 4; ++qt) ot[d][qt] = (f32x4){0.f, 0.f, 0.f, 0.f};
  #pragma unroll
  for (int jt = 0; jt < 4; ++jt)
    #pragma unroll
    for (int d = 0; d < 2; ++d)
      #pragma unroll
      for (int qt = 0; qt < 4; ++qt)
        ot[d][qt] = MFMA16(Vh[jt][d], pf[jt][qt], ot[d][qt]);

  // ---- normalize, bounce O^T -> row-major per-wave LDS, coalesced copy-out ----
  h16* Ob = (h16*)(lds + wave * 5120);   // per-wave [64][40]; aliases dead staging
  #pragma unroll
  for (int d = 0; d < 2; ++d)
    #pragma unroll
    for (int qt = 0; qt < 4; ++qt) {
      h16x4 ov;
      #pragma unroll
      for (int r = 0; r < 4; ++r) ov[r] = (h16)(ot[d][qt][r] * rinv[qt]);
      *(h16x4*)(Ob + (16 * qt + l15) * 40 + 16 * d + 4 * lg) = ov;
    }
  if (lane < 49) {
    h16* gdst = O + (rowbase + lane) * 512 + head * 32;
    #pragma unroll
    for (int c = 0; c < 4; ++c)
      *(h16x8*)(gdst + c * 8) = *(const h16x8*)(Ob + lane * 40 + c * 8);
  }
}

// ---------------- output projection: out = O @ w2 + proj_b ----------------
// 128x128 tile, 4 waves of 64x64, BK=64, x32 MFMAs, swizzled LDS, T14 prefetch.
__global__ __launch_bounds__(256, 3) void wa_proj(
    const h16* __restrict__ O, const h16* __restrict__ w2T,
    const float* __restrict__ proj_b, float* __restrict__ out) {
  __shared__ __align__(16) char lds[32768];
  char* Ac = lds;            // [128 rows][64 k] h16, swizzled
  char* Bc = lds + 16384;    // [128 cols][64 k] h16, swizzled
  const int tid = threadIdx.x;
  const int wave = tid >> 6, lane = tid & 63;
  const int l15 = lane & 15, lg = lane >> 4;
  const int lbid = (blockIdx.x & 7) * 784 + (blockIdx.x >> 3);  // XCD swizzle (6272 % 8 == 0)
  const int rowt = lbid >> 2, colt = lbid & 3;
  const int wr = wave >> 1, wc = wave & 1;

  f32x4 acc[4][4];
  #pragma unroll
  for (int a = 0; a < 4; ++a)
    #pragma unroll
    for (int b = 0; b < 4; ++b) acc[a][b] = (f32x4){0.f, 0.f, 0.f, 0.f};

  h16x8 pre[8];
  #pragma unroll
  for (int p = 0; p < 8; ++p) {          // prologue load tile 0
    int idx = tid + p * 256;
    int r = (idx >> 3) & 127, c = idx & 7;
    pre[p] = (idx < 1024)
        ? *(const h16x8*)(O   + (size_t)(rowt * 128 + r) * 512 + c * 8)
        : *(const h16x8*)(w2T + (size_t)(colt * 128 + r) * 512 + c * 8);
  }
  #pragma unroll
  for (int p = 0; p < 8; ++p) {
    int idx = tid + p * 256;
    int r = (idx >> 3) & 127, c = idx & 7;
    char* dst = ((idx < 1024) ? Ac : Bc) + r * 128 + ((c ^ (r & 7)) << 4);
    *(h16x8*)dst = pre[p];
  }
  __syncthreads();

  for (int kt = 0; kt < 8; ++kt) {
    if (kt < 7) {
      #pragma unroll
      for (int p = 0; p < 8; ++p) {
        int idx = tid + p * 256;
        int r = (idx >> 3) & 127, c = idx & 7;
        pre[p] = (idx < 1024)
            ? *(const h16x8*)(O   + (size_t)(rowt * 128 + r) * 512 + (kt + 1) * 64 + c * 8)
            : *(const h16x8*)(w2T + (size_t)(colt * 128 + r) * 512 + (kt + 1) * 64 + c * 8);
      }
    }
    #pragma unroll
    for (int kh = 0; kh < 2; ++kh) {
      const int cc = kh * 4 + lg;
      const int sw = (l15 & 7);
      h16x8 af[4], bf[4];
      #pragma unroll
      for (int mt = 0; mt < 4; ++mt) {
        int r = wr * 64 + 16 * mt + l15;
        af[mt] = *(const h16x8*)(Ac + r * 128 + ((cc ^ sw) << 4));
      }
      #pragma unroll
      for (int nt = 0; nt < 4; ++nt) {
        int r = wc * 64 + 16 * nt + l15;
        bf[nt] = *(const h16x8*)(Bc + r * 128 + ((cc ^ sw) << 4));
      }
      #pragma unroll
      for (int mt = 0; mt < 4; ++mt)
        #pragma unroll
        for (int nt = 0; nt < 4; ++nt)
          acc[mt][nt] = MFMA32(af[mt], bf[nt], acc[mt][nt]);
    }
    __syncthreads();
    if (kt < 7) {
      #pragma unroll
      for (int p = 0; p < 8; ++p) {
        int idx = tid + p * 256;
        int r = (idx >> 3) & 127, c = idx & 7;
        char* dst = ((idx < 1024) ? Ac : Bc) + r * 128 + ((c ^ (r & 7)) << 4);
        *(h16x8*)dst = pre[p];
      }
      __syncthreads();
    }
  }
  #pragma unroll
  for (int nt = 0; nt < 4; ++nt) {
    int col = colt * 128 + wc * 64 + nt * 16 + l15;
    float pb = proj_b[col];
    #pragma unroll
    for (int mt = 0; mt < 4; ++mt) {
      int row = rowt * 128 + wr * 64 + mt * 16 + 4 * lg;
      #pragma unroll
      for (int r = 0; r < 4; ++r)
        out[(size_t)(row + r) * 512 + col] = acc[mt][nt][r] + pb;
    }
  }
}

extern "C" void kernel_launch(void* const* d_in, const int* in_sizes, int n_in,
                              void* d_out, int out_size, void* d_ws, size_t ws_size,
                              hipStream_t stream) {
  const float* x          = (const float*)d_in[0];
  const float* qkv_w      = (const float*)d_in[1];
  const float* qkv_b      = (const float*)d_in[2];
  const float* proj_w     = (const float*)d_in[3];
  const float* proj_b     = (const float*)d_in[4];
  const float* bias_table = (const float*)d_in[5];
  float* out = (float*)d_out;

  char* ws = (char*)d_ws;
  h16*   O     = (h16*)ws;
  h16*   w1T   = (h16*)(ws + W1T_OFF);
  h16*   w2T   = (h16*)(ws + W2T_OFF);
  float* biasT = (float*)(ws + BT_OFF);
  h16*   x16   = (h16*)d_out;  // d_out is dead until wa_proj overwrites it

  wa_convert_x<<<50176, 256, 0, stream>>>(x, x16);
  wa_transpose_w1<<<768, 256, 0, stream>>>(qkv_w, w1T);
  wa_transpose_w2<<<256, 256, 0, stream>>>(proj_w, w2T);
  wa_build_bias<<<256, 256, 0, stream>>>(bias_table, biasT);
  wa_qkv_attn<<<4096 * 4, 256, 0, stream>>>(x16, qkv_b, w1T, biasT, O);
  wa_proj<<<1568 * 4, 256, 0, stream>>>(O, w2T, proj_b, out);
}

// Round 5
// 1224.725 us; speedup vs baseline: 1.4968x; 1.0847x over previous
//
#include <hip/hip_runtime.h>

typedef _Float16 h16;
typedef __attribute__((ext_vector_type(4))) _Float16 h16x4;
typedef __attribute__((ext_vector_type(8))) _Float16 h16x8;
typedef __attribute__((ext_vector_type(4))) float f32x4;

#define SCALE 0.17677669529663687f
#define MFMA16(a, b, c) __builtin_amdgcn_mfma_f32_16x16x16f16(a, b, c, 0, 0, 0)
#define MFMA32(a, b, c) __builtin_amdgcn_mfma_f32_16x16x32_f16(a, b, c, 0, 0, 0)

// workspace layout (bytes)
#define O_BYTES 205520896ULL              // 200704*512*2 (pre-proj output, fp16)
#define W1T_OFF (O_BYTES)                 // w1T fp16 [1536][512]: 1572864
#define W2T_OFF (W1T_OFF + 1572864ULL)    // w2T fp16 [512 out][512 k]: 524288
#define BT_OFF  (W2T_OFF + 524288ULL)     // biasT f32 [16][64 q][64 j]: 262144

// ---------------- x fp32 -> fp16 (into d_out; dead until wa_proj overwrites) ----------------
__global__ __launch_bounds__(256) void wa_convert_x(
    const float* __restrict__ x, h16* __restrict__ x16) {
  size_t i = ((size_t)blockIdx.x * 256 + threadIdx.x) * 8;
  float4 a = *(const float4*)(x + i);
  float4 b = *(const float4*)(x + i + 4);
  h16x8 h = { (h16)a.x, (h16)a.y, (h16)a.z, (h16)a.w,
              (h16)b.x, (h16)b.y, (h16)b.z, (h16)b.w };
  *(h16x8*)(x16 + i) = h;
}

// ---------------- qkv_w [512c][1536o] fp32 -> w1T [1536o][512c] fp16 ----------------
__global__ __launch_bounds__(256) void wa_transpose_w1(
    const float* __restrict__ qkv_w, h16* __restrict__ w1T) {
  __shared__ h16 T[32][33];
  int tx = threadIdx.x & 31, ty = threadIdx.x >> 5;   // 32 x 8
  int bo = blockIdx.x % 48, bc = blockIdx.x / 48;     // 48 o-tiles, 16 c-tiles
  #pragma unroll
  for (int i = 0; i < 4; ++i) {
    int c = bc * 32 + ty + 8 * i, o = bo * 32 + tx;
    T[ty + 8 * i][tx] = (h16)qkv_w[c * 1536 + o];
  }
  __syncthreads();
  #pragma unroll
  for (int i = 0; i < 4; ++i) {
    int o_l = ty + 8 * i;
    w1T[(size_t)(bo * 32 + o_l) * 512 + bc * 32 + tx] = T[tx][o_l];
  }
}

// ---------------- proj_w [512c][512o] fp32 -> w2T [512o][512c] fp16 ----------------
__global__ __launch_bounds__(256) void wa_transpose_w2(
    const float* __restrict__ proj_w, h16* __restrict__ w2T) {
  __shared__ h16 T[32][33];
  int tx = threadIdx.x & 31, ty = threadIdx.x >> 5;
  int bo = blockIdx.x & 15, bc = blockIdx.x >> 4;     // 16 x 16 tiles
  #pragma unroll
  for (int i = 0; i < 4; ++i) {
    int c = bc * 32 + ty + 8 * i, o = bo * 32 + tx;
    T[ty + 8 * i][tx] = (h16)proj_w[c * 512 + o];
  }
  __syncthreads();
  #pragma unroll
  for (int i = 0; i < 4; ++i) {
    int o_l = ty + 8 * i;
    w2T[(size_t)(bo * 32 + o_l) * 512 + bc * 32 + tx] = T[tx][o_l];
  }
}

// ---------------- relative-position bias: biasT[h][q][j], -1e30 where padded ----------------
__global__ __launch_bounds__(256) void wa_build_bias(
    const float* __restrict__ table, float* __restrict__ biasT) {
  int idx = blockIdx.x * 256 + threadIdx.x;  // 65536
  int h = idx >> 12, q = (idx >> 6) & 63, j = idx & 63;
  float v = -1e30f;
  if (j < 49 && q < 49) {
    int rel = (q / 7 - j / 7 + 6) * 13 + (q % 7 - j % 7 + 6);
    v = table[rel * 16 + h];
  }
  biasT[idx] = v;
}

// ---------------- fused QKV projection + window attention ----------------
// grid: 4096 windows * 4 head-groups (XCD-swizzled); block 256 = 4 waves; wave = one head.
// X staged ONCE in LDS (64x512 fp16, 64 KiB, chunk-XOR swizzle); W fragments read
// DIRECTLY from L2 into registers (slice is L2-resident). K-loop has ZERO barriers
// and ZERO LDS writes; W loads software-pipelined 2-deep (named bufs, static idx).
__global__ __launch_bounds__(256, 2) void wa_qkv_attn(
    const h16* __restrict__ x16, const float* __restrict__ qkv_b,
    const h16* __restrict__ w1T, const float* __restrict__ biasT,
    h16* __restrict__ O) {
  __shared__ __align__(16) char lds[65536];   // X: [64 rows][64 chunks of 16B], swizzled
  const int tid = threadIdx.x;
  const int wave = tid >> 6, lane = tid & 63;
  const int l15 = lane & 15, lg = lane >> 4;
  const int sw = l15 & 7;
  const int lbid = (blockIdx.x & 7) * 2048 + (blockIdx.x >> 3);  // XCD swizzle (16384 % 8 == 0)
  const int w = lbid >> 2, g = lbid & 3;
  const int head = g * 4 + wave;
  const size_t rowbase = (size_t)w * 49;

  // ---- stage X fully: rows 0..48 from global, rows 49..63 zeroed ----
  #pragma unroll
  for (int p = 0; p < 13; ++p) {
    int idx = tid + p * 256;
    if (idx < 3136) {
      int r = idx >> 6, c = idx & 63;
      *(h16x8*)(lds + r * 1024 + ((c ^ (r & 7)) << 4)) =
          *(const h16x8*)(x16 + (rowbase + r) * 512 + c * 8);
    }
  }
  #pragma unroll
  for (int p = 0; p < 4; ++p) {
    int idx = tid + p * 256;
    if (idx < 960) {
      int r = 49 + (idx >> 6), c = idx & 63;
      *(h16x8*)(lds + r * 1024 + ((c ^ (r & 7)) << 4)) = (h16x8){0,0,0,0,0,0,0,0};
    }
  }
  __syncthreads();

  f32x4 accQ[2][4], accK[2][4], accV[4][2];
  #pragma unroll
  for (int d = 0; d < 2; ++d)
    #pragma unroll
    for (int t = 0; t < 4; ++t) {
      accQ[d][t] = (f32x4){0.f, 0.f, 0.f, 0.f};
      accK[d][t] = (f32x4){0.f, 0.f, 0.f, 0.f};
      accV[t][d] = (f32x4){0.f, 0.f, 0.f, 0.f};
    }

  // per-lane W base: row (g*128 + wave*32 + l15), k-chunk lg
  const h16* wb = w1T + (size_t)(g * 128 + wave * 32 + l15) * 512 + lg * 8;
  // per-lane X read bases (byte offsets into lds)
  int xb[4];
  #pragma unroll
  for (int t = 0; t < 4; ++t) xb[t] = (16 * t + l15) * 1024;
  const int co0 = ((lg) ^ sw) << 4, co1 = ((4 + lg) ^ sw) << 4;

  // W frag index: [s*4 + d*2 + ks], s: 0=Q 1=K 2=V
  h16x8 WA[12], WB[12];
#define WLOAD(DST, KT) {                                                   \
    _Pragma("unroll") for (int s = 0; s < 3; ++s)                          \
    _Pragma("unroll") for (int d = 0; d < 2; ++d)                          \
    _Pragma("unroll") for (int ks = 0; ks < 2; ++ks)                       \
      DST[s*4 + d*2 + ks] =                                                \
        *(const h16x8*)(wb + s * 262144 + d * 8192 + (KT) * 64 + ks * 32); }

#define GSTEP(KT, W) {                                                     \
    h16x8 xf[4];                                                           \
    _Pragma("unroll") for (int t = 0; t < 4; ++t)                          \
      xf[t] = *(const h16x8*)(lds + xb[t] + co0 + (KT) * 128);             \
    _Pragma("unroll") for (int d = 0; d < 2; ++d)                          \
    _Pragma("unroll") for (int t = 0; t < 4; ++t) {                        \
      accQ[d][t] = MFMA32(W[0 + d*2], xf[t], accQ[d][t]);                  \
      accK[d][t] = MFMA32(W[4 + d*2], xf[t], accK[d][t]);                  \
      accV[t][d] = MFMA32(xf[t], W[8 + d*2], accV[t][d]);                  \
    }                                                                      \
    _Pragma("unroll") for (int t = 0; t < 4; ++t)                          \
      xf[t] = *(const h16x8*)(lds + xb[t] + co1 + (KT) * 128);             \
    _Pragma("unroll") for (int d = 0; d < 2; ++d)                          \
    _Pragma("unroll") for (int t = 0; t < 4; ++t) {                        \
      accQ[d][t] = MFMA32(W[1 + d*2], xf[t], accQ[d][t]);                  \
      accK[d][t] = MFMA32(W[5 + d*2], xf[t], accK[d][t]);                  \
      accV[t][d] = MFMA32(xf[t], W[9 + d*2], accV[t][d]);                  \
    } }

  WLOAD(WA, 0);
  for (int kt2 = 0; kt2 < 4; ++kt2) {
    WLOAD(WB, 2 * kt2 + 1);
    GSTEP(2 * kt2, WA);
    if (kt2 < 3) WLOAD(WA, 2 * kt2 + 2);
    GSTEP(2 * kt2 + 1, WB);
  }

  // ---- per-head biases ----
  float bq[2][4], bk[2][4], bv[2];
  #pragma unroll
  for (int d = 0; d < 2; ++d) {
    #pragma unroll
    for (int r = 0; r < 4; ++r) {
      bq[d][r] = qkv_b[head * 32 + 16 * d + 4 * lg + r];
      bk[d][r] = qkv_b[512 + head * 32 + 16 * d + 4 * lg + r];
    }
    bv[d] = qkv_b[1024 + head * 32 + 16 * d + l15];
  }
  const float* bT = biasT + head * 4096;

  // ---- epilogue: bias (+scale Q), convert to fp16 operand frags in registers ----
  h16x4 Qh[2][4], Kh[2][4], Vh[4][2];
  #pragma unroll
  for (int d = 0; d < 2; ++d)
    #pragma unroll
    for (int t = 0; t < 4; ++t)
      #pragma unroll
      for (int r = 0; r < 4; ++r) {
        Qh[d][t][r] = (h16)((accQ[d][t][r] + bq[d][r]) * SCALE);
        Kh[d][t][r] = (h16)(accK[d][t][r] + bk[d][r]);
        Vh[t][d][r] = (h16)(accV[t][d][r] + bv[d]);
      }

  // ---- S^T = K Q^T (register operands) ----
  f32x4 st[4][4];
  #pragma unroll
  for (int a = 0; a < 4; ++a)
    #pragma unroll
    for (int b = 0; b < 4; ++b) st[a][b] = (f32x4){0.f, 0.f, 0.f, 0.f};
  #pragma unroll
  for (int d = 0; d < 2; ++d)
    #pragma unroll
    for (int jt = 0; jt < 4; ++jt)
      #pragma unroll
      for (int qt = 0; qt < 4; ++qt)
        st[jt][qt] = MFMA16(Kh[d][jt], Qh[d][qt], st[jt][qt]);

  // ---- bias + in-register softmax over j ----
  float rinv[4];
  #pragma unroll
  for (int qt = 0; qt < 4; ++qt) {
    int q = 16 * qt + l15;
    float mx = -3.4e38f;
    #pragma unroll
    for (int jt = 0; jt < 4; ++jt) {
      float4 bvv = *(const float4*)(bT + q * 64 + 16 * jt + 4 * lg);
      #pragma unroll
      for (int r = 0; r < 4; ++r) {
        float v = st[jt][qt][r] + ((const float*)&bvv)[r];
        st[jt][qt][r] = v;
        mx = fmaxf(mx, v);
      }
    }
    mx = fmaxf(mx, __shfl_xor(mx, 16, 64));
    mx = fmaxf(mx, __shfl_xor(mx, 32, 64));
    float sum = 0.f;
    #pragma unroll
    for (int jt = 0; jt < 4; ++jt)
      #pragma unroll
      for (int r = 0; r < 4; ++r) {
        float p = __expf(st[jt][qt][r] - mx);
        st[jt][qt][r] = p;
        sum += p;
      }
    sum += __shfl_xor(sum, 16, 64);
    sum += __shfl_xor(sum, 32, 64);
    rinv[qt] = 1.0f / sum;
  }

  // P^T frags already in B-operand layout
  h16x4 pf[4][4];
  #pragma unroll
  for (int jt = 0; jt < 4; ++jt)
    #pragma unroll
    for (int qt = 0; qt < 4; ++qt)
      pf[jt][qt] = (h16x4){ (h16)st[jt][qt][0], (h16)st[jt][qt][1],
                            (h16)st[jt][qt][2], (h16)st[jt][qt][3] };

  // ---- O^T = V^T P^T ----
  f32x4 ot[2][4];
  #pragma unroll
  for (int d = 0; d < 2; ++d)
    #pragma unroll
    for (int qt = 0; qt < 4; ++qt) ot[d][qt] = (f32x4){0.f, 0.f, 0.f, 0.f};
  #pragma unroll
  for (int jt = 0; jt < 4; ++jt)
    #pragma unroll
    for (int d = 0; d < 2; ++d)
      #pragma unroll
      for (int qt = 0; qt < 4; ++qt)
        ot[d][qt] = MFMA16(Vh[jt][d], pf[jt][qt], ot[d][qt]);

  // ---- one barrier: all waves done reading X; then reuse LDS for output bounce ----
  __syncthreads();
  h16* Ob = (h16*)(lds + wave * 5120);   // per-wave [64][40]
  #pragma unroll
  for (int d = 0; d < 2; ++d)
    #pragma unroll
    for (int qt = 0; qt < 4; ++qt) {
      h16x4 ov;
      #pragma unroll
      for (int r = 0; r < 4; ++r) ov[r] = (h16)(ot[d][qt][r] * rinv[qt]);
      *(h16x4*)(Ob + (16 * qt + l15) * 40 + 16 * d + 4 * lg) = ov;
    }
  if (lane < 49) {
    h16* gdst = O + (rowbase + lane) * 512 + head * 32;
    #pragma unroll
    for (int c = 0; c < 4; ++c)
      *(h16x8*)(gdst + c * 8) = *(const h16x8*)(Ob + lane * 40 + c * 8);
  }
}

// ---------------- output projection: out = O @ w2 + proj_b ----------------
// 128x128 tile, 4 waves of 64x64, BK=64, x32 MFMAs, swizzled LDS, reg prefetch.
__global__ __launch_bounds__(256, 3) void wa_proj(
    const h16* __restrict__ O, const h16* __restrict__ w2T,
    const float* __restrict__ proj_b, float* __restrict__ out) {
  __shared__ __align__(16) char lds[32768];
  char* Ac = lds;            // [128 rows][64 k] h16, swizzled
  char* Bc = lds + 16384;    // [128 cols][64 k] h16, swizzled
  const int tid = threadIdx.x;
  const int wave = tid >> 6, lane = tid & 63;
  const int l15 = lane & 15, lg = lane >> 4;
  const int lbid = (blockIdx.x & 7) * 784 + (blockIdx.x >> 3);  // XCD swizzle (6272 % 8 == 0)
  const int rowt = lbid >> 2, colt = lbid & 3;
  const int wr = wave >> 1, wc = wave & 1;

  f32x4 acc[4][4];
  #pragma unroll
  for (int a = 0; a < 4; ++a)
    #pragma unroll
    for (int b = 0; b < 4; ++b) acc[a][b] = (f32x4){0.f, 0.f, 0.f, 0.f};

  h16x8 pre[8];
  #pragma unroll
  for (int p = 0; p < 8; ++p) {          // prologue load tile 0
    int idx = tid + p * 256;
    int r = (idx >> 3) & 127, c = idx & 7;
    pre[p] = (idx < 1024)
        ? *(const h16x8*)(O   + (size_t)(rowt * 128 + r) * 512 + c * 8)
        : *(const h16x8*)(w2T + (size_t)(colt * 128 + r) * 512 + c * 8);
  }
  #pragma unroll
  for (int p = 0; p < 8; ++p) {
    int idx = tid + p * 256;
    int r = (idx >> 3) & 127, c = idx & 7;
    char* dst = ((idx < 1024) ? Ac : Bc) + r * 128 + ((c ^ (r & 7)) << 4);
    *(h16x8*)dst = pre[p];
  }
  __syncthreads();

  for (int kt = 0; kt < 8; ++kt) {
    if (kt < 7) {
      #pragma unroll
      for (int p = 0; p < 8; ++p) {
        int idx = tid + p * 256;
        int r = (idx >> 3) & 127, c = idx & 7;
        pre[p] = (idx < 1024)
            ? *(const h16x8*)(O   + (size_t)(rowt * 128 + r) * 512 + (kt + 1) * 64 + c * 8)
            : *(const h16x8*)(w2T + (size_t)(colt * 128 + r) * 512 + (kt + 1) * 64 + c * 8);
      }
    }
    #pragma unroll
    for (int kh = 0; kh < 2; ++kh) {
      const int cc = kh * 4 + lg;
      const int sw = (l15 & 7);
      h16x8 af[4], bf[4];
      #pragma unroll
      for (int mt = 0; mt < 4; ++mt) {
        int r = wr * 64 + 16 * mt + l15;
        af[mt] = *(const h16x8*)(Ac + r * 128 + ((cc ^ sw) << 4));
      }
      #pragma unroll
      for (int nt = 0; nt < 4; ++nt) {
        int r = wc * 64 + 16 * nt + l15;
        bf[nt] = *(const h16x8*)(Bc + r * 128 + ((cc ^ sw) << 4));
      }
      #pragma unroll
      for (int mt = 0; mt < 4; ++mt)
        #pragma unroll
        for (int nt = 0; nt < 4; ++nt)
          acc[mt][nt] = MFMA32(af[mt], bf[nt], acc[mt][nt]);
    }
    __syncthreads();
    if (kt < 7) {
      #pragma unroll
      for (int p = 0; p < 8; ++p) {
        int idx = tid + p * 256;
        int r = (idx >> 3) & 127, c = idx & 7;
        char* dst = ((idx < 1024) ? Ac : Bc) + r * 128 + ((c ^ (r & 7)) << 4);
        *(h16x8*)dst = pre[p];
      }
      __syncthreads();
    }
  }
  #pragma unroll
  for (int nt = 0; nt < 4; ++nt) {
    int col = colt * 128 + wc * 64 + nt * 16 + l15;
    float pb = proj_b[col];
    #pragma unroll
    for (int mt = 0; mt < 4; ++mt) {
      int row = rowt * 128 + wr * 64 + mt * 16 + 4 * lg;
      #pragma unroll
      for (int r = 0; r < 4; ++r)
        out[(size_t)(row + r) * 512 + col] = acc[mt][nt][r] + pb;
    }
  }
}

extern "C" void kernel_launch(void* const* d_in, const int* in_sizes, int n_in,
                              void* d_out, int out_size, void* d_ws, size_t ws_size,
                              hipStream_t stream) {
  const float* x          = (const float*)d_in[0];
  const float* qkv_w      = (const float*)d_in[1];
  const float* qkv_b      = (const float*)d_in[2];
  const float* proj_w     = (const float*)d_in[3];
  const float* proj_b     = (const float*)d_in[4];
  const float* bias_table = (const float*)d_in[5];
  float* out = (float*)d_out;

  char* ws = (char*)d_ws;
  h16*   O     = (h16*)ws;
  h16*   w1T   = (h16*)(ws + W1T_OFF);
  h16*   w2T   = (h16*)(ws + W2T_OFF);
  float* biasT = (float*)(ws + BT_OFF);
  h16*   x16   = (h16*)d_out;  // d_out is dead until wa_proj overwrites it

  wa_convert_x<<<50176, 256, 0, stream>>>(x, x16);
  wa_transpose_w1<<<768, 256, 0, stream>>>(qkv_w, w1T);
  wa_transpose_w2<<<256, 256, 0, stream>>>(proj_w, w2T);
  wa_build_bias<<<256, 256, 0, stream>>>(bias_table, biasT);
  wa_qkv_attn<<<4096 * 4, 256, 0, stream>>>(x16, qkv_b, w1T, biasT, O);
  wa_proj<<<1568 * 4, 256, 0, stream>>>(O, w2T, proj_b, out);
}